// Round 6
// baseline (1179.995 us; speedup 1.0000x reference)
//
#include <hip/hip_runtime.h>
#include <hip/hip_bf16.h>
#include <math.h>

#define CAP 64     // col slots per node (real edges; slot CAP-1 conceptually = self-loop)
#define NB  1024   // radix buckets (dst >> 7)

// ---------------- adjacency build: dst-radix bucketing, then fill ----------------

__global__ void hist_kernel(const int* __restrict__ ei, int* __restrict__ bhist, int E) {
    int idx = blockIdx.x * blockDim.x + threadIdx.x;
    if (idx >= E) return;
    atomicAdd(&bhist[ei[E + idx] >> 7], 1);
}

__global__ void scan_kernel(const int* __restrict__ bhist, int* __restrict__ bcur) {
    __shared__ int s[NB];
    int t = threadIdx.x;
    int v = bhist[t];
    s[t] = v;
    __syncthreads();
    #pragma unroll
    for (int d = 1; d < NB; d <<= 1) {
        int u = (t >= d) ? s[t - d] : 0;
        __syncthreads();
        s[t] += u;
        __syncthreads();
    }
    bcur[t] = s[t] - v;   // exclusive prefix
}

__global__ void scatter_kernel(const int* __restrict__ ei, int* __restrict__ bcur,
                               int2* __restrict__ sorted, int E) {
    int idx = blockIdx.x * blockDim.x + threadIdx.x;
    if (idx >= E) return;
    int s = ei[idx];
    int d = ei[E + idx];
    int pos = atomicAdd(&bcur[d >> 7], 1);
    sorted[pos] = make_int2(s, d);
}

__global__ void fill_sorted_kernel(const int2* __restrict__ sorted, int* __restrict__ deg,
                                   int* __restrict__ col, int E) {
    int idx = blockIdx.x * blockDim.x + threadIdx.x;
    if (idx >= E) return;
    int2 e = sorted[idx];
    int pos = atomicAdd(&deg[e.y], 1);
    if (pos < CAP - 1) col[(size_t)e.y * CAP + pos] = e.x;
}

// ---------------- per-layer dense: h = x @ W, es = h.a_s, ed = h.a_d ----------------
// lane = output feature; W column in VGPRs; x rows loaded coalesced then
// broadcast via v_readlane into v_fma's SGPR operand slot.

__device__ __forceinline__ float rl(float v, int l) {
    return __int_as_float(__builtin_amdgcn_readlane(__float_as_int(v), l));
}

template<int K>
__global__ __launch_bounds__(256, 2) void gemm_h_kernel(
        const float* __restrict__ x, const float* __restrict__ W,
        const float* __restrict__ a_s, const float* __restrict__ a_d,
        float* __restrict__ h, float* __restrict__ es, float* __restrict__ ed, int n) {
    constexpr int K4 = K / 4;
    constexpr int RW = 8;
    constexpr int NLD = RW * K4 / 64;

    int tid = threadIdx.x;
    int lane = tid & 63;
    float w[K];
    #pragma unroll
    for (int k = 0; k < K; ++k) w[k] = W[k * 64 + lane];
    float asv = a_s[lane];
    float adv = a_d[lane];

    int wid = (blockIdx.x * 256 + tid) >> 6;
    int nwaves = (gridDim.x * 256) >> 6;
    int ngroups = (n + RW - 1) / RW;

    for (int g = wid; g < ngroups; g += nwaves) {
        int r0 = g * RW;
        float4 xr[NLD];
        #pragma unroll
        for (int i = 0; i < NLD; ++i) {
            int flat = i * 64 + lane;
            int r = flat / K4, k4 = flat % K4;
            int row = r0 + r; if (row >= n) row = n - 1;
            xr[i] = *(const float4*)(x + (size_t)row * K + k4 * 4);
        }
        #pragma unroll
        for (int r = 0; r < RW; ++r) {
            float acc0 = 0.f, acc1 = 0.f, acc2 = 0.f, acc3 = 0.f;
            #pragma unroll
            for (int k4 = 0; k4 < K4; ++k4) {
                int flat = r * K4 + k4;
                int reg = flat >> 6, src = flat & 63;
                float4 v = xr[reg];
                acc0 = fmaf(rl(v.x, src), w[4 * k4 + 0], acc0);
                acc1 = fmaf(rl(v.y, src), w[4 * k4 + 1], acc1);
                acc2 = fmaf(rl(v.z, src), w[4 * k4 + 2], acc2);
                acc3 = fmaf(rl(v.w, src), w[4 * k4 + 3], acc3);
            }
            int row = r0 + r;
            float a = (acc0 + acc1) + (acc2 + acc3);
            float ps = a * asv;
            float pd = a * adv;
            #pragma unroll
            for (int off = 32; off; off >>= 1) {
                ps += __shfl_xor(ps, off);
                pd += __shfl_xor(pd, off);
            }
            if (row < n) {
                h[(size_t)row * 64 + lane] = a;
                if (lane == 0) { es[row] = ps; ed[row] = pd; }
            }
        }
    }
}

// ---------------- per-dst softmax aggregation, H=64, one wave per node ----------------
// Implicit self-loop at lane==cr; 8 independent accumulators for MLP.

__global__ __launch_bounds__(256) void aggregate64_kernel(
        const float* __restrict__ h, const float* __restrict__ es, const float* __restrict__ ed,
        const int* __restrict__ deg, const int* __restrict__ col,
        const float* __restrict__ bias, float* __restrict__ xout, int n, int do_relu) {
    int lane = threadIdx.x & 63;
    int node = (blockIdx.x * blockDim.x + threadIdx.x) >> 6;
    if (node >= n) return;
    int cr = deg[node]; if (cr > CAP - 1) cr = CAP - 1;   // real edges
    int cnt = cr + 1;                                     // + self-loop
    float edi = ed[node];

    int s = 0;
    float e = -INFINITY;
    if (lane < cr) {
        s = col[(size_t)node * CAP + lane];
        float t = es[s] + edi;
        e = (t >= 0.f) ? t : 0.2f * t;          // leaky_relu 0.2
    } else if (lane == cr) {
        s = node;
        float t = es[node] + edi;
        e = (t >= 0.f) ? t : 0.2f * t;
    }
    float m = e;
    #pragma unroll
    for (int off = 32; off; off >>= 1) m = fmaxf(m, __shfl_xor(m, off));
    float p = __expf(e - m);                    // 0 for invalid lanes
    float denom = p;
    #pragma unroll
    for (int off = 32; off; off >>= 1) denom += __shfl_xor(denom, off);

    float a0 = 0.f, a1 = 0.f, a2 = 0.f, a3 = 0.f;
    float a4 = 0.f, a5 = 0.f, a6 = 0.f, a7 = 0.f;
    int iters = (cnt + 7) & ~7;
    for (int j = 0; j < iters; j += 8) {
        float p0 = __shfl(p, j + 0); int s0 = __shfl(s, j + 0);
        float p1 = __shfl(p, j + 1); int s1 = __shfl(s, j + 1);
        float p2 = __shfl(p, j + 2); int s2 = __shfl(s, j + 2);
        float p3 = __shfl(p, j + 3); int s3 = __shfl(s, j + 3);
        float p4 = __shfl(p, j + 4); int s4 = __shfl(s, j + 4);
        float p5 = __shfl(p, j + 5); int s5 = __shfl(s, j + 5);
        float p6 = __shfl(p, j + 6); int s6 = __shfl(s, j + 6);
        float p7 = __shfl(p, j + 7); int s7 = __shfl(s, j + 7);
        a0 = fmaf(p0, h[(size_t)s0 * 64 + lane], a0);
        a1 = fmaf(p1, h[(size_t)s1 * 64 + lane], a1);
        a2 = fmaf(p2, h[(size_t)s2 * 64 + lane], a2);
        a3 = fmaf(p3, h[(size_t)s3 * 64 + lane], a3);
        a4 = fmaf(p4, h[(size_t)s4 * 64 + lane], a4);
        a5 = fmaf(p5, h[(size_t)s5 * 64 + lane], a5);
        a6 = fmaf(p6, h[(size_t)s6 * 64 + lane], a6);
        a7 = fmaf(p7, h[(size_t)s7 * 64 + lane], a7);
    }
    float o = (((a0 + a1) + (a2 + a3)) + ((a4 + a5) + (a6 + a7))) / denom + bias[lane];
    if (do_relu) o = fmaxf(o, 0.f);
    xout[(size_t)node * 64 + lane] = o;
}

// ---------------- last layer (OUT=1) ----------------

__global__ __launch_bounds__(256) void gemm_hl_kernel(
        const float* __restrict__ x, const float* __restrict__ Wl,
        float* __restrict__ hl, int n) {
    int lane = threadIdx.x & 63;
    int row = (blockIdx.x * blockDim.x + threadIdx.x) >> 6;
    if (row >= n) return;
    float p = x[(size_t)row * 64 + lane] * Wl[lane];
    #pragma unroll
    for (int off = 32; off; off >>= 1) p += __shfl_xor(p, off);
    if (lane == 0) hl[row] = p;
}

__global__ __launch_bounds__(256) void aggregate1_kernel(
        const float* __restrict__ hl, const float* __restrict__ asl,
        const float* __restrict__ adl, const float* __restrict__ bl,
        const int* __restrict__ deg, const int* __restrict__ col,
        float* __restrict__ out, int n) {
    int lane = threadIdx.x & 63;
    int node = (blockIdx.x * blockDim.x + threadIdx.x) >> 6;
    if (node >= n) return;
    float As = asl[0], Ad = adl[0], B = bl[0];
    int cr = deg[node]; if (cr > CAP - 1) cr = CAP - 1;
    float edi = hl[node] * Ad;

    float hs = 0.f;
    float e = -INFINITY;
    if (lane < cr) {
        int s = col[(size_t)node * CAP + lane];
        hs = hl[s];
        float t = fmaf(hs, As, edi);
        e = (t >= 0.f) ? t : 0.2f * t;
    } else if (lane == cr) {
        hs = hl[node];
        float t = fmaf(hs, As, edi);
        e = (t >= 0.f) ? t : 0.2f * t;
    }
    float m = e;
    #pragma unroll
    for (int off = 32; off; off >>= 1) m = fmaxf(m, __shfl_xor(m, off));
    float p = __expf(e - m);
    float d = p;
    float a = p * hs;
    #pragma unroll
    for (int off = 32; off; off >>= 1) {
        d += __shfl_xor(d, off);
        a += __shfl_xor(a, off);
    }
    if (lane == 0) out[node] = a / d + B;
}

// ---------------- launch ----------------

extern "C" void kernel_launch(void* const* d_in, const int* in_sizes, int n_in,
                              void* d_out, int out_size, void* d_ws, size_t ws_size,
                              hipStream_t stream) {
    const float* x0  = (const float*)d_in[0];
    const int*   ei  = (const int*)d_in[1];
    const float* W0  = (const float*)d_in[3];
    const float* as0 = (const float*)d_in[4];
    const float* ad0 = (const float*)d_in[5];
    const float* b0  = (const float*)d_in[6];
    const float* W1  = (const float*)d_in[7];
    const float* as1 = (const float*)d_in[8];
    const float* ad1 = (const float*)d_in[9];
    const float* b1  = (const float*)d_in[10];
    const float* W2  = (const float*)d_in[11];
    const float* as2 = (const float*)d_in[12];
    const float* ad2 = (const float*)d_in[13];
    const float* b2  = (const float*)d_in[14];
    const float* Wl  = (const float*)d_in[15];
    const float* asl = (const float*)d_in[16];
    const float* adl = (const float*)d_in[17];
    const float* bl  = (const float*)d_in[18];

    int n = in_sizes[0] / 128;
    int E = in_sizes[1] / 2;

    char* p = (char*)d_ws;
    auto alloc = [&](size_t bytes) { char* r = p; p += (bytes + 255) & ~255ULL; return r; };
    float* h     = (float*)alloc((size_t)n * 64 * 4);
    float* xb    = (float*)alloc((size_t)n * 64 * 4);   // also aliases `sorted` during build
    int*   col   = (int*)alloc((size_t)n * CAP * 4);
    float* es    = (float*)alloc((size_t)n * 4);
    float* ed    = (float*)alloc((size_t)n * 4);
    float* hl    = (float*)alloc((size_t)n * 4);
    int*   deg   = (int*)alloc((size_t)n * 4);
    int*   bhist = (int*)alloc(NB * 4);
    int*   bcur  = (int*)alloc(NB * 4);
    int2*  sorted = (int2*)xb;                          // E*8 B = 12.8 MB <= 25.6 MB
    (void)ws_size; (void)n_in; (void)out_size;

    int eb = (E + 255) / 256;
    int agg_blocks = (n + 3) / 4;

    hipMemsetAsync(deg, 0, (size_t)n * 4, stream);
    hipMemsetAsync(bhist, 0, NB * 4, stream);

    hist_kernel<<<eb, 256, 0, stream>>>(ei, bhist, E);
    scan_kernel<<<1, NB, 0, stream>>>(bhist, bcur);
    scatter_kernel<<<eb, 256, 0, stream>>>(ei, bcur, sorted, E);
    fill_sorted_kernel<<<eb, 256, 0, stream>>>(sorted, deg, col, E);

    // layer 0
    gemm_h_kernel<128><<<2048, 256, 0, stream>>>(x0, W0, as0, ad0, h, es, ed, n);
    aggregate64_kernel<<<agg_blocks, 256, 0, stream>>>(h, es, ed, deg, col, b0, xb, n, 1);
    // layer 1
    gemm_h_kernel<64><<<2048, 256, 0, stream>>>(xb, W1, as1, ad1, h, es, ed, n);
    aggregate64_kernel<<<agg_blocks, 256, 0, stream>>>(h, es, ed, deg, col, b1, xb, n, 1);
    // layer 2
    gemm_h_kernel<64><<<2048, 256, 0, stream>>>(xb, W2, as2, ad2, h, es, ed, n);
    aggregate64_kernel<<<agg_blocks, 256, 0, stream>>>(h, es, ed, deg, col, b2, xb, n, 1);
    // final layer
    gemm_hl_kernel<<<agg_blocks, 256, 0, stream>>>(xb, Wl, hl, n);
    aggregate1_kernel<<<agg_blocks, 256, 0, stream>>>(hl, asl, adl, bl, deg, col,
                                                      (float*)d_out, n);
}

// Round 7
// 510.896 us; speedup vs baseline: 2.3097x; 2.3097x over previous
//
#include <hip/hip_runtime.h>
#include <hip/hip_bf16.h>
#include <math.h>

#define CAP 64   // col slots per node; slots 0..CAP-2 = real edges, self-loop implicit

// ---------------- adjacency fill: 1 edge per thread, deg pre-zeroed ----------------

__global__ void fill_fixed_kernel(const int* __restrict__ ei, int* __restrict__ deg,
                                  int* __restrict__ col, int E) {
    int idx = blockIdx.x * blockDim.x + threadIdx.x;
    if (idx >= E) return;
    int s = ei[idx];
    int d = ei[E + idx];
    int pos = atomicAdd(&deg[d], 1);
    if (pos < CAP - 1) col[(size_t)d * CAP + pos] = s;
}

// ---------------- per-layer dense: h = x @ W, es = h.a_s, ed = h.a_d ----------------

__device__ __forceinline__ float rl(float v, int l) {
    return __int_as_float(__builtin_amdgcn_readlane(__float_as_int(v), l));
}

template<int K>
__global__ __launch_bounds__(256, 2) void gemm_h_kernel(
        const float* __restrict__ x, const float* __restrict__ W,
        const float* __restrict__ a_s, const float* __restrict__ a_d,
        float* __restrict__ h, float* __restrict__ es, float* __restrict__ ed, int n) {
    constexpr int K4 = K / 4;
    constexpr int RW = 8;
    constexpr int NLD = RW * K4 / 64;

    int tid = threadIdx.x;
    int lane = tid & 63;
    float w[K];
    #pragma unroll
    for (int k = 0; k < K; ++k) w[k] = W[k * 64 + lane];
    float asv = a_s[lane];
    float adv = a_d[lane];

    int wid = (blockIdx.x * 256 + tid) >> 6;
    int nwaves = (gridDim.x * 256) >> 6;
    int ngroups = (n + RW - 1) / RW;

    for (int g = wid; g < ngroups; g += nwaves) {
        int r0 = g * RW;
        float4 xr[NLD];
        #pragma unroll
        for (int i = 0; i < NLD; ++i) {
            int flat = i * 64 + lane;
            int r = flat / K4, k4 = flat % K4;
            int row = r0 + r; if (row >= n) row = n - 1;
            xr[i] = *(const float4*)(x + (size_t)row * K + k4 * 4);
        }
        #pragma unroll
        for (int r = 0; r < RW; ++r) {
            float acc0 = 0.f, acc1 = 0.f, acc2 = 0.f, acc3 = 0.f;
            #pragma unroll
            for (int k4 = 0; k4 < K4; ++k4) {
                int flat = r * K4 + k4;
                int reg = flat >> 6, src = flat & 63;
                float4 v = xr[reg];
                acc0 = fmaf(rl(v.x, src), w[4 * k4 + 0], acc0);
                acc1 = fmaf(rl(v.y, src), w[4 * k4 + 1], acc1);
                acc2 = fmaf(rl(v.z, src), w[4 * k4 + 2], acc2);
                acc3 = fmaf(rl(v.w, src), w[4 * k4 + 3], acc3);
            }
            int row = r0 + r;
            float a = (acc0 + acc1) + (acc2 + acc3);
            float ps = a * asv;
            float pd = a * adv;
            #pragma unroll
            for (int off = 32; off; off >>= 1) {
                ps += __shfl_xor(ps, off);
                pd += __shfl_xor(pd, off);
            }
            if (row < n) {
                h[(size_t)row * 64 + lane] = a;
                if (lane == 0) { es[row] = ps; ed[row] = pd; }
            }
        }
    }
}

// ---------------- per-dst softmax aggregation, H=64, one wave per node ----------------
// Implicit self-loop at lane==cr; 16 independent accumulators (MLP probe).

__global__ __launch_bounds__(256) void aggregate64_kernel(
        const float* __restrict__ h, const float* __restrict__ es, const float* __restrict__ ed,
        const int* __restrict__ deg, const int* __restrict__ col,
        const float* __restrict__ bias, float* __restrict__ xout, int n, int do_relu) {
    int lane = threadIdx.x & 63;
    int node = (blockIdx.x * blockDim.x + threadIdx.x) >> 6;
    if (node >= n) return;
    int cr = deg[node]; if (cr > CAP - 1) cr = CAP - 1;   // real edges
    int cnt = cr + 1;                                     // + self-loop
    float edi = ed[node];

    int s = 0;
    float e = -INFINITY;
    if (lane < cr) {
        s = col[(size_t)node * CAP + lane];
        float t = es[s] + edi;
        e = (t >= 0.f) ? t : 0.2f * t;          // leaky_relu 0.2
    } else if (lane == cr) {
        s = node;
        float t = es[node] + edi;
        e = (t >= 0.f) ? t : 0.2f * t;
    }
    float m = e;
    #pragma unroll
    for (int off = 32; off; off >>= 1) m = fmaxf(m, __shfl_xor(m, off));
    float p = __expf(e - m);                    // 0 for invalid lanes
    float denom = p;
    #pragma unroll
    for (int off = 32; off; off >>= 1) denom += __shfl_xor(denom, off);

    float acc[16];
    #pragma unroll
    for (int i = 0; i < 16; ++i) acc[i] = 0.f;
    int iters = (cnt + 15) & ~15;
    for (int j = 0; j < iters; j += 16) {
        #pragma unroll
        for (int i = 0; i < 16; ++i) {
            float pi = __shfl(p, j + i);
            int si = __shfl(s, j + i);
            acc[i] = fmaf(pi, h[(si << 6) | lane], acc[i]);
        }
    }
    float o = (((acc[0] + acc[1]) + (acc[2] + acc[3])) + ((acc[4] + acc[5]) + (acc[6] + acc[7])))
            + (((acc[8] + acc[9]) + (acc[10] + acc[11])) + ((acc[12] + acc[13]) + (acc[14] + acc[15])));
    o = o / denom + bias[lane];
    if (do_relu) o = fmaxf(o, 0.f);
    xout[(size_t)node * 64 + lane] = o;
}

// ---------------- last layer (OUT=1) ----------------

__global__ __launch_bounds__(256) void gemm_hl_kernel(
        const float* __restrict__ x, const float* __restrict__ Wl,
        float* __restrict__ hl, int n) {
    int lane = threadIdx.x & 63;
    int row = (blockIdx.x * blockDim.x + threadIdx.x) >> 6;
    if (row >= n) return;
    float p = x[(size_t)row * 64 + lane] * Wl[lane];
    #pragma unroll
    for (int off = 32; off; off >>= 1) p += __shfl_xor(p, off);
    if (lane == 0) hl[row] = p;
}

__global__ __launch_bounds__(256) void aggregate1_kernel(
        const float* __restrict__ hl, const float* __restrict__ asl,
        const float* __restrict__ adl, const float* __restrict__ bl,
        const int* __restrict__ deg, const int* __restrict__ col,
        float* __restrict__ out, int n) {
    int lane = threadIdx.x & 63;
    int node = (blockIdx.x * blockDim.x + threadIdx.x) >> 6;
    if (node >= n) return;
    float As = asl[0], Ad = adl[0], B = bl[0];
    int cr = deg[node]; if (cr > CAP - 1) cr = CAP - 1;
    float edi = hl[node] * Ad;

    float hs = 0.f;
    float e = -INFINITY;
    if (lane < cr) {
        int s = col[(size_t)node * CAP + lane];
        hs = hl[s];
        float t = fmaf(hs, As, edi);
        e = (t >= 0.f) ? t : 0.2f * t;
    } else if (lane == cr) {
        hs = hl[node];
        float t = fmaf(hs, As, edi);
        e = (t >= 0.f) ? t : 0.2f * t;
    }
    float m = e;
    #pragma unroll
    for (int off = 32; off; off >>= 1) m = fmaxf(m, __shfl_xor(m, off));
    float p = __expf(e - m);
    float d = p;
    float a = p * hs;
    #pragma unroll
    for (int off = 32; off; off >>= 1) {
        d += __shfl_xor(d, off);
        a += __shfl_xor(a, off);
    }
    if (lane == 0) out[node] = a / d + B;
}

// ---------------- launch ----------------

extern "C" void kernel_launch(void* const* d_in, const int* in_sizes, int n_in,
                              void* d_out, int out_size, void* d_ws, size_t ws_size,
                              hipStream_t stream) {
    const float* x0  = (const float*)d_in[0];
    const int*   ei  = (const int*)d_in[1];
    const float* W0  = (const float*)d_in[3];
    const float* as0 = (const float*)d_in[4];
    const float* ad0 = (const float*)d_in[5];
    const float* b0  = (const float*)d_in[6];
    const float* W1  = (const float*)d_in[7];
    const float* as1 = (const float*)d_in[8];
    const float* ad1 = (const float*)d_in[9];
    const float* b1  = (const float*)d_in[10];
    const float* W2  = (const float*)d_in[11];
    const float* as2 = (const float*)d_in[12];
    const float* ad2 = (const float*)d_in[13];
    const float* b2  = (const float*)d_in[14];
    const float* Wl  = (const float*)d_in[15];
    const float* asl = (const float*)d_in[16];
    const float* adl = (const float*)d_in[17];
    const float* bl  = (const float*)d_in[18];

    int n = in_sizes[0] / 128;
    int E = in_sizes[1] / 2;

    char* p = (char*)d_ws;
    auto alloc = [&](size_t bytes) { char* r = p; p += (bytes + 255) & ~255ULL; return r; };
    float* h   = (float*)alloc((size_t)n * 64 * 4);
    float* xb  = (float*)alloc((size_t)n * 64 * 4);
    int*   col = (int*)alloc((size_t)n * CAP * 4);
    float* es  = (float*)alloc((size_t)n * 4);
    float* ed  = (float*)alloc((size_t)n * 4);
    float* hl  = (float*)alloc((size_t)n * 4);
    int*   deg = (int*)alloc((size_t)n * 4);
    (void)ws_size; (void)n_in; (void)out_size;

    int agg_blocks = (n + 3) / 4;

    hipMemsetAsync(deg, 0, (size_t)n * 4, stream);
    fill_fixed_kernel<<<(E + 255) / 256, 256, 0, stream>>>(ei, deg, col, E);

    // layer 0
    gemm_h_kernel<128><<<2048, 256, 0, stream>>>(x0, W0, as0, ad0, h, es, ed, n);
    aggregate64_kernel<<<agg_blocks, 256, 0, stream>>>(h, es, ed, deg, col, b0, xb, n, 1);
    // layer 1
    gemm_h_kernel<64><<<2048, 256, 0, stream>>>(xb, W1, as1, ad1, h, es, ed, n);
    aggregate64_kernel<<<agg_blocks, 256, 0, stream>>>(h, es, ed, deg, col, b1, xb, n, 1);
    // layer 2
    gemm_h_kernel<64><<<2048, 256, 0, stream>>>(xb, W2, as2, ad2, h, es, ed, n);
    aggregate64_kernel<<<agg_blocks, 256, 0, stream>>>(h, es, ed, deg, col, b2, xb, n, 1);
    // final layer
    gemm_hl_kernel<<<agg_blocks, 256, 0, stream>>>(xb, Wl, hl, n);
    aggregate1_kernel<<<agg_blocks, 256, 0, stream>>>(hl, asl, adl, bl, deg, col,
                                                      (float*)d_out, n);
}

// Round 8
// 443.185 us; speedup vs baseline: 2.6625x; 1.1528x over previous
//
#include <hip/hip_runtime.h>
#include <hip/hip_bf16.h>
#include <math.h>

#define CAP 64   // col slots per node; slots 0..CAP-2 = real edges, self-loop implicit

// ---------------- adjacency fill: XCD-partitioned filtering ----------------
// partition = blockIdx & 7 (matches bid%8 -> XCD round-robin); an edge belongs
// to partition (dst>>4)&7, so each 64B deg line and each node's col region is
// written by exactly one partition -> col lines fill completely inside one
// XCD's L2 before write-back.

__global__ __launch_bounds__(256) void fill_part_kernel(
        const int* __restrict__ ei, int* __restrict__ deg,
        int* __restrict__ col, int E, int nchunk) {
    int part = blockIdx.x & 7;
    int chunk = blockIdx.x >> 3;
    int per = (E + nchunk - 1) / nchunk;
    int lo = chunk * per;
    int hi = lo + per; if (hi > E) hi = E;
    for (int idx = lo + threadIdx.x; idx < hi; idx += 256) {
        int d = ei[E + idx];
        if (((d >> 4) & 7) == part) {
            int s = ei[idx];
            int pos = atomicAdd(&deg[d], 1);
            if (pos < CAP - 1) col[(size_t)d * CAP + pos] = s;
        }
    }
}

// ---------------- per-layer dense: h = x @ W, es = h.a_s, ed = h.a_d ----------------

__device__ __forceinline__ float rl(float v, int l) {
    return __int_as_float(__builtin_amdgcn_readlane(__float_as_int(v), l));
}

template<int K>
__global__ __launch_bounds__(256, 2) void gemm_h_kernel(
        const float* __restrict__ x, const float* __restrict__ W,
        const float* __restrict__ a_s, const float* __restrict__ a_d,
        float* __restrict__ h, float* __restrict__ es, float* __restrict__ ed, int n) {
    constexpr int K4 = K / 4;
    constexpr int RW = 8;
    constexpr int NLD = RW * K4 / 64;

    int tid = threadIdx.x;
    int lane = tid & 63;
    float w[K];
    #pragma unroll
    for (int k = 0; k < K; ++k) w[k] = W[k * 64 + lane];
    float asv = a_s[lane];
    float adv = a_d[lane];

    int wid = (blockIdx.x * 256 + tid) >> 6;
    int nwaves = (gridDim.x * 256) >> 6;
    int ngroups = (n + RW - 1) / RW;

    for (int g = wid; g < ngroups; g += nwaves) {
        int r0 = g * RW;
        float4 xr[NLD];
        #pragma unroll
        for (int i = 0; i < NLD; ++i) {
            int flat = i * 64 + lane;
            int r = flat / K4, k4 = flat % K4;
            int row = r0 + r; if (row >= n) row = n - 1;
            xr[i] = *(const float4*)(x + (size_t)row * K + k4 * 4);
        }
        #pragma unroll
        for (int r = 0; r < RW; ++r) {
            float acc0 = 0.f, acc1 = 0.f, acc2 = 0.f, acc3 = 0.f;
            #pragma unroll
            for (int k4 = 0; k4 < K4; ++k4) {
                int flat = r * K4 + k4;
                int reg = flat >> 6, src = flat & 63;
                float4 v = xr[reg];
                acc0 = fmaf(rl(v.x, src), w[4 * k4 + 0], acc0);
                acc1 = fmaf(rl(v.y, src), w[4 * k4 + 1], acc1);
                acc2 = fmaf(rl(v.z, src), w[4 * k4 + 2], acc2);
                acc3 = fmaf(rl(v.w, src), w[4 * k4 + 3], acc3);
            }
            int row = r0 + r;
            float a = (acc0 + acc1) + (acc2 + acc3);
            float ps = a * asv;
            float pd = a * adv;
            #pragma unroll
            for (int off = 32; off; off >>= 1) {
                ps += __shfl_xor(ps, off);
                pd += __shfl_xor(pd, off);
            }
            if (row < n) {
                h[(size_t)row * 64 + lane] = a;
                if (lane == 0) { es[row] = ps; ed[row] = pd; }
            }
        }
    }
}

// ---------------- per-dst softmax aggregation, H=64, one wave per node ----------------
// Implicit self-loop at lane==cr. PROJ=true fuses the final 64->1 projection
// (hl[node] = dot(out_row, Wl)) and skips the 25.6MB xout write.

template<bool PROJ>
__global__ __launch_bounds__(256) void aggregate64_kernel(
        const float* __restrict__ h, const float* __restrict__ es, const float* __restrict__ ed,
        const int* __restrict__ deg, const int* __restrict__ col,
        const float* __restrict__ bias, float* __restrict__ xout, int n, int do_relu,
        const float* __restrict__ Wl, float* __restrict__ hl) {
    int lane = threadIdx.x & 63;
    int node = (blockIdx.x * blockDim.x + threadIdx.x) >> 6;
    if (node >= n) return;
    int cr = deg[node]; if (cr > CAP - 1) cr = CAP - 1;   // real edges
    int cnt = cr + 1;                                     // + self-loop
    float edi = ed[node];

    int s = 0;
    float e = -INFINITY;
    if (lane < cr) {
        s = col[(size_t)node * CAP + lane];
        float t = es[s] + edi;
        e = (t >= 0.f) ? t : 0.2f * t;          // leaky_relu 0.2
    } else if (lane == cr) {
        s = node;
        float t = es[node] + edi;
        e = (t >= 0.f) ? t : 0.2f * t;
    }
    float m = e;
    #pragma unroll
    for (int off = 32; off; off >>= 1) m = fmaxf(m, __shfl_xor(m, off));
    float p = __expf(e - m);                    // 0 for invalid lanes
    float denom = p;
    #pragma unroll
    for (int off = 32; off; off >>= 1) denom += __shfl_xor(denom, off);

    float a0 = 0.f, a1 = 0.f, a2 = 0.f, a3 = 0.f;
    float a4 = 0.f, a5 = 0.f, a6 = 0.f, a7 = 0.f;
    int iters = (cnt + 7) & ~7;
    for (int j = 0; j < iters; j += 8) {
        float p0 = __shfl(p, j + 0); int s0 = __shfl(s, j + 0);
        float p1 = __shfl(p, j + 1); int s1 = __shfl(s, j + 1);
        float p2 = __shfl(p, j + 2); int s2 = __shfl(s, j + 2);
        float p3 = __shfl(p, j + 3); int s3 = __shfl(s, j + 3);
        float p4 = __shfl(p, j + 4); int s4 = __shfl(s, j + 4);
        float p5 = __shfl(p, j + 5); int s5 = __shfl(s, j + 5);
        float p6 = __shfl(p, j + 6); int s6 = __shfl(s, j + 6);
        float p7 = __shfl(p, j + 7); int s7 = __shfl(s, j + 7);
        a0 = fmaf(p0, h[(s0 << 6) | lane], a0);
        a1 = fmaf(p1, h[(s1 << 6) | lane], a1);
        a2 = fmaf(p2, h[(s2 << 6) | lane], a2);
        a3 = fmaf(p3, h[(s3 << 6) | lane], a3);
        a4 = fmaf(p4, h[(s4 << 6) | lane], a4);
        a5 = fmaf(p5, h[(s5 << 6) | lane], a5);
        a6 = fmaf(p6, h[(s6 << 6) | lane], a6);
        a7 = fmaf(p7, h[(s7 << 6) | lane], a7);
    }
    float o = (((a0 + a1) + (a2 + a3)) + ((a4 + a5) + (a6 + a7))) / denom + bias[lane];
    if (do_relu) o = fmaxf(o, 0.f);
    if constexpr (PROJ) {
        float ph = o * Wl[lane];
        #pragma unroll
        for (int off = 32; off; off >>= 1) ph += __shfl_xor(ph, off);
        if (lane == 0) hl[node] = ph;
    } else {
        xout[(size_t)node * 64 + lane] = o;
    }
}

// ---------------- final layer (OUT=1) aggregation ----------------

__global__ __launch_bounds__(256) void aggregate1_kernel(
        const float* __restrict__ hl, const float* __restrict__ asl,
        const float* __restrict__ adl, const float* __restrict__ bl,
        const int* __restrict__ deg, const int* __restrict__ col,
        float* __restrict__ out, int n) {
    int lane = threadIdx.x & 63;
    int node = (blockIdx.x * blockDim.x + threadIdx.x) >> 6;
    if (node >= n) return;
    float As = asl[0], Ad = adl[0], B = bl[0];
    int cr = deg[node]; if (cr > CAP - 1) cr = CAP - 1;
    float edi = hl[node] * Ad;

    float hs = 0.f;
    float e = -INFINITY;
    if (lane < cr) {
        int s = col[(size_t)node * CAP + lane];
        hs = hl[s];
        float t = fmaf(hs, As, edi);
        e = (t >= 0.f) ? t : 0.2f * t;
    } else if (lane == cr) {
        hs = hl[node];
        float t = fmaf(hs, As, edi);
        e = (t >= 0.f) ? t : 0.2f * t;
    }
    float m = e;
    #pragma unroll
    for (int off = 32; off; off >>= 1) m = fmaxf(m, __shfl_xor(m, off));
    float p = __expf(e - m);
    float d = p;
    float a = p * hs;
    #pragma unroll
    for (int off = 32; off; off >>= 1) {
        d += __shfl_xor(d, off);
        a += __shfl_xor(a, off);
    }
    if (lane == 0) out[node] = a / d + B;
}

// ---------------- launch ----------------

extern "C" void kernel_launch(void* const* d_in, const int* in_sizes, int n_in,
                              void* d_out, int out_size, void* d_ws, size_t ws_size,
                              hipStream_t stream) {
    const float* x0  = (const float*)d_in[0];
    const int*   ei  = (const int*)d_in[1];
    const float* W0  = (const float*)d_in[3];
    const float* as0 = (const float*)d_in[4];
    const float* ad0 = (const float*)d_in[5];
    const float* b0  = (const float*)d_in[6];
    const float* W1  = (const float*)d_in[7];
    const float* as1 = (const float*)d_in[8];
    const float* ad1 = (const float*)d_in[9];
    const float* b1  = (const float*)d_in[10];
    const float* W2  = (const float*)d_in[11];
    const float* as2 = (const float*)d_in[12];
    const float* ad2 = (const float*)d_in[13];
    const float* b2  = (const float*)d_in[14];
    const float* Wl  = (const float*)d_in[15];
    const float* asl = (const float*)d_in[16];
    const float* adl = (const float*)d_in[17];
    const float* bl  = (const float*)d_in[18];

    int n = in_sizes[0] / 128;
    int E = in_sizes[1] / 2;

    char* p = (char*)d_ws;
    auto alloc = [&](size_t bytes) { char* r = p; p += (bytes + 255) & ~255ULL; return r; };
    float* h   = (float*)alloc((size_t)n * 64 * 4);
    float* xb  = (float*)alloc((size_t)n * 64 * 4);
    int*   col = (int*)alloc((size_t)n * CAP * 4);
    float* es  = (float*)alloc((size_t)n * 4);
    float* ed  = (float*)alloc((size_t)n * 4);
    float* hl  = (float*)alloc((size_t)n * 4);
    int*   deg = (int*)alloc((size_t)n * 4);
    (void)ws_size; (void)n_in; (void)out_size;

    int agg_blocks = (n + 3) / 4;

    hipMemsetAsync(deg, 0, (size_t)n * 4, stream);
    fill_part_kernel<<<8 * 512, 256, 0, stream>>>(ei, deg, col, E, 512);

    // layer 0
    gemm_h_kernel<128><<<2048, 256, 0, stream>>>(x0, W0, as0, ad0, h, es, ed, n);
    aggregate64_kernel<false><<<agg_blocks, 256, 0, stream>>>(h, es, ed, deg, col, b0,
                                                              xb, n, 1, nullptr, nullptr);
    // layer 1
    gemm_h_kernel<64><<<2048, 256, 0, stream>>>(xb, W1, as1, ad1, h, es, ed, n);
    aggregate64_kernel<false><<<agg_blocks, 256, 0, stream>>>(h, es, ed, deg, col, b1,
                                                              xb, n, 1, nullptr, nullptr);
    // layer 2
    gemm_h_kernel<64><<<2048, 256, 0, stream>>>(xb, W2, as2, ad2, h, es, ed, n);
    // layer-2 aggregate fused with Wl projection -> hl
    aggregate64_kernel<true><<<agg_blocks, 256, 0, stream>>>(h, es, ed, deg, col, b2,
                                                             nullptr, n, 1, Wl, hl);
    // final layer aggregation (OUT=1)
    aggregate1_kernel<<<agg_blocks, 256, 0, stream>>>(hl, asl, adl, bl, deg, col,
                                                      (float*)d_out, n);
}

// Round 9
// 370.726 us; speedup vs baseline: 3.1829x; 1.1955x over previous
//
#include <hip/hip_runtime.h>
#include <hip/hip_bf16.h>
#include <math.h>

#define CAP 64   // col slots per node; slots 0..CAP-2 = real edges, self-loop implicit

typedef __attribute__((ext_vector_type(8))) short bf16x8;
typedef __attribute__((ext_vector_type(4))) float f32x4;

// float -> bf16 bits (RNE) and back
__device__ __forceinline__ short f2b(float f) {
    unsigned u = __float_as_uint(f);
    unsigned r = (u + 0x7FFFu + ((u >> 16) & 1u)) >> 16;
    return (short)r;
}
__device__ __forceinline__ float b2f(short b) {
    return __uint_as_float(((unsigned)(unsigned short)b) << 16);
}

// ---------------- adjacency fill: XCD-partitioned filtering ----------------

__global__ __launch_bounds__(256) void fill_part_kernel(
        const int* __restrict__ ei, int* __restrict__ deg,
        int* __restrict__ col, int E, int nchunk) {
    int part = blockIdx.x & 7;
    int chunk = blockIdx.x >> 3;
    int per = (E + nchunk - 1) / nchunk;
    int lo = chunk * per;
    int hi = lo + per; if (hi > E) hi = E;
    for (int idx = lo + threadIdx.x; idx < hi; idx += 256) {
        int d = ei[E + idx];
        if (((d >> 4) & 7) == part) {
            int s = ei[idx];
            int pos = atomicAdd(&deg[d], 1);
            if (pos < CAP - 1) col[(size_t)d * CAP + pos] = s;
        }
    }
}

// ---------------- MFMA dense layer: h = x @ W (bf16x3 split), es/ed fused ----------------
// Wave tile: 16 rows x 64 cols. A-frag: lane holds x[row0 + (l&15)][ks*32 + (l>>4)*8 + j].
// B-frag: lane holds W[ks*32 + (l>>4)*8 + j][nf*16 + (l&15)] (same k schedule as A).
// C/D (HW-verified): value reg r of lane l = h[row0 + (l>>4)*4 + r][nf*16 + (l&15)].
// h = xh*wh + xh*wl + xl*wh  (lo*lo dropped, ~2^-18 relative error).

template<int K>
__global__ __launch_bounds__(256) void gemm_mfma_kernel(
        const float* __restrict__ x, const float* __restrict__ W,
        const float* __restrict__ a_s, const float* __restrict__ a_d,
        float* __restrict__ h, float* __restrict__ es, float* __restrict__ ed, int n) {
    constexpr int NK = K / 32;
    // LDS B fragments: [hi/lo][nf][ks][lane][8]
    __shared__ short bfrag[2 * 4 * NK * 64 * 8];
    constexpr int HALF = 4 * NK * 64 * 8;

    int tid = threadIdx.x;
    int lane = tid & 63;
    int l15 = lane & 15;
    int lg = lane >> 4;          // 0..3

    if (tid < 64) {              // wave 0 packs all B fragments once
        for (int nf = 0; nf < 4; ++nf) {
            for (int ks = 0; ks < NK; ++ks) {
                int base = ((nf * NK + ks) * 64 + lane) * 8;
                #pragma unroll
                for (int j = 0; j < 8; ++j) {
                    float wv = W[(ks * 32 + lg * 8 + j) * 64 + nf * 16 + l15];
                    short hb = f2b(wv);
                    bfrag[base + j] = hb;
                    bfrag[HALF + base + j] = f2b(wv - b2f(hb));
                }
            }
        }
    }
    __syncthreads();

    float asv[4], adv[4];
    #pragma unroll
    for (int nf = 0; nf < 4; ++nf) {
        asv[nf] = a_s[nf * 16 + l15];
        adv[nf] = a_d[nf * 16 + l15];
    }

    int wid = (blockIdx.x * 256 + tid) >> 6;
    int nw = (gridDim.x * 256) >> 6;
    int ntiles = (n + 15) / 16;

    for (int t = wid; t < ntiles; t += nw) {
        int row0 = t * 16;
        int row = row0 + l15; if (row >= n) row = n - 1;
        const float* xr = x + (size_t)row * K + lg * 8;

        bf16x8 ahi[NK], alo[NK];
        #pragma unroll
        for (int ks = 0; ks < NK; ++ks) {
            float4 v0 = *(const float4*)(xr + ks * 32);
            float4 v1 = *(const float4*)(xr + ks * 32 + 4);
            float xv[8] = {v0.x, v0.y, v0.z, v0.w, v1.x, v1.y, v1.z, v1.w};
            #pragma unroll
            for (int j = 0; j < 8; ++j) {
                short hb = f2b(xv[j]);
                ahi[ks][j] = hb;
                alo[ks][j] = f2b(xv[j] - b2f(hb));
            }
        }

        f32x4 accs[4];
        #pragma unroll
        for (int nf = 0; nf < 4; ++nf) {
            f32x4 acc = {0.f, 0.f, 0.f, 0.f};
            #pragma unroll
            for (int ks = 0; ks < NK; ++ks) {
                bf16x8 bh = *(bf16x8*)&bfrag[((nf * NK + ks) * 64 + lane) * 8];
                bf16x8 bl = *(bf16x8*)&bfrag[HALF + ((nf * NK + ks) * 64 + lane) * 8];
                acc = __builtin_amdgcn_mfma_f32_16x16x32_bf16(ahi[ks], bh, acc, 0, 0, 0);
                acc = __builtin_amdgcn_mfma_f32_16x16x32_bf16(ahi[ks], bl, acc, 0, 0, 0);
                acc = __builtin_amdgcn_mfma_f32_16x16x32_bf16(alo[ks], bh, acc, 0, 0, 0);
            }
            accs[nf] = acc;
        }

        #pragma unroll
        for (int r = 0; r < 4; ++r) {
            int orow = row0 + lg * 4 + r;
            float ps = 0.f, pd = 0.f;
            if (orow < n) {
                #pragma unroll
                for (int nf = 0; nf < 4; ++nf) {
                    float hv = accs[nf][r];
                    h[(size_t)orow * 64 + nf * 16 + l15] = hv;
                    ps = fmaf(hv, asv[nf], ps);
                    pd = fmaf(hv, adv[nf], pd);
                }
            }
            #pragma unroll
            for (int off = 8; off; off >>= 1) {
                ps += __shfl_xor(ps, off);
                pd += __shfl_xor(pd, off);
            }
            if (l15 == 0 && orow < n) { es[orow] = ps; ed[orow] = pd; }
        }
    }
}

// ---------------- per-dst softmax aggregation, H=64, one wave per node ----------------
// Implicit self-loop at lane==cr. PROJ=true fuses the final 64->1 projection.

template<bool PROJ>
__global__ __launch_bounds__(256) void aggregate64_kernel(
        const float* __restrict__ h, const float* __restrict__ es, const float* __restrict__ ed,
        const int* __restrict__ deg, const int* __restrict__ col,
        const float* __restrict__ bias, float* __restrict__ xout, int n, int do_relu,
        const float* __restrict__ Wl, float* __restrict__ hl) {
    int lane = threadIdx.x & 63;
    int node = (blockIdx.x * blockDim.x + threadIdx.x) >> 6;
    if (node >= n) return;
    int cr = deg[node]; if (cr > CAP - 1) cr = CAP - 1;   // real edges
    int cnt = cr + 1;                                     // + self-loop
    float edi = ed[node];

    int s = 0;
    float e = -INFINITY;
    if (lane < cr) {
        s = col[(size_t)node * CAP + lane];
        float t = es[s] + edi;
        e = (t >= 0.f) ? t : 0.2f * t;          // leaky_relu 0.2
    } else if (lane == cr) {
        s = node;
        float t = es[node] + edi;
        e = (t >= 0.f) ? t : 0.2f * t;
    }
    float m = e;
    #pragma unroll
    for (int off = 32; off; off >>= 1) m = fmaxf(m, __shfl_xor(m, off));
    float p = __expf(e - m);                    // 0 for invalid lanes
    float denom = p;
    #pragma unroll
    for (int off = 32; off; off >>= 1) denom += __shfl_xor(denom, off);

    float a0 = 0.f, a1 = 0.f, a2 = 0.f, a3 = 0.f;
    float a4 = 0.f, a5 = 0.f, a6 = 0.f, a7 = 0.f;
    int iters = (cnt + 7) & ~7;
    for (int j = 0; j < iters; j += 8) {
        float p0 = __shfl(p, j + 0); int s0 = __shfl(s, j + 0);
        float p1 = __shfl(p, j + 1); int s1 = __shfl(s, j + 1);
        float p2 = __shfl(p, j + 2); int s2 = __shfl(s, j + 2);
        float p3 = __shfl(p, j + 3); int s3 = __shfl(s, j + 3);
        float p4 = __shfl(p, j + 4); int s4 = __shfl(s, j + 4);
        float p5 = __shfl(p, j + 5); int s5 = __shfl(s, j + 5);
        float p6 = __shfl(p, j + 6); int s6 = __shfl(s, j + 6);
        float p7 = __shfl(p, j + 7); int s7 = __shfl(s, j + 7);
        a0 = fmaf(p0, h[(s0 << 6) | lane], a0);
        a1 = fmaf(p1, h[(s1 << 6) | lane], a1);
        a2 = fmaf(p2, h[(s2 << 6) | lane], a2);
        a3 = fmaf(p3, h[(s3 << 6) | lane], a3);
        a4 = fmaf(p4, h[(s4 << 6) | lane], a4);
        a5 = fmaf(p5, h[(s5 << 6) | lane], a5);
        a6 = fmaf(p6, h[(s6 << 6) | lane], a6);
        a7 = fmaf(p7, h[(s7 << 6) | lane], a7);
    }
    float o = (((a0 + a1) + (a2 + a3)) + ((a4 + a5) + (a6 + a7))) / denom + bias[lane];
    if (do_relu) o = fmaxf(o, 0.f);
    if constexpr (PROJ) {
        float ph = o * Wl[lane];
        #pragma unroll
        for (int off = 32; off; off >>= 1) ph += __shfl_xor(ph, off);
        if (lane == 0) hl[node] = ph;
    } else {
        xout[(size_t)node * 64 + lane] = o;
    }
}

// ---------------- final layer (OUT=1) aggregation ----------------

__global__ __launch_bounds__(256) void aggregate1_kernel(
        const float* __restrict__ hl, const float* __restrict__ asl,
        const float* __restrict__ adl, const float* __restrict__ bl,
        const int* __restrict__ deg, const int* __restrict__ col,
        float* __restrict__ out, int n) {
    int lane = threadIdx.x & 63;
    int node = (blockIdx.x * blockDim.x + threadIdx.x) >> 6;
    if (node >= n) return;
    float As = asl[0], Ad = adl[0], B = bl[0];
    int cr = deg[node]; if (cr > CAP - 1) cr = CAP - 1;
    float edi = hl[node] * Ad;

    float hs = 0.f;
    float e = -INFINITY;
    if (lane < cr) {
        int s = col[(size_t)node * CAP + lane];
        hs = hl[s];
        float t = fmaf(hs, As, edi);
        e = (t >= 0.f) ? t : 0.2f * t;
    } else if (lane == cr) {
        hs = hl[node];
        float t = fmaf(hs, As, edi);
        e = (t >= 0.f) ? t : 0.2f * t;
    }
    float m = e;
    #pragma unroll
    for (int off = 32; off; off >>= 1) m = fmaxf(m, __shfl_xor(m, off));
    float p = __expf(e - m);
    float d = p;
    float a = p * hs;
    #pragma unroll
    for (int off = 32; off; off >>= 1) {
        d += __shfl_xor(d, off);
        a += __shfl_xor(a, off);
    }
    if (lane == 0) out[node] = a / d + B;
}

// ---------------- launch ----------------

extern "C" void kernel_launch(void* const* d_in, const int* in_sizes, int n_in,
                              void* d_out, int out_size, void* d_ws, size_t ws_size,
                              hipStream_t stream) {
    const float* x0  = (const float*)d_in[0];
    const int*   ei  = (const int*)d_in[1];
    const float* W0  = (const float*)d_in[3];
    const float* as0 = (const float*)d_in[4];
    const float* ad0 = (const float*)d_in[5];
    const float* b0  = (const float*)d_in[6];
    const float* W1  = (const float*)d_in[7];
    const float* as1 = (const float*)d_in[8];
    const float* ad1 = (const float*)d_in[9];
    const float* b1  = (const float*)d_in[10];
    const float* W2  = (const float*)d_in[11];
    const float* as2 = (const float*)d_in[12];
    const float* ad2 = (const float*)d_in[13];
    const float* b2  = (const float*)d_in[14];
    const float* Wl  = (const float*)d_in[15];
    const float* asl = (const float*)d_in[16];
    const float* adl = (const float*)d_in[17];
    const float* bl  = (const float*)d_in[18];

    int n = in_sizes[0] / 128;
    int E = in_sizes[1] / 2;

    char* p = (char*)d_ws;
    auto alloc = [&](size_t bytes) { char* r = p; p += (bytes + 255) & ~255ULL; return r; };
    float* h   = (float*)alloc((size_t)n * 64 * 4);
    float* xb  = (float*)alloc((size_t)n * 64 * 4);
    int*   col = (int*)alloc((size_t)n * CAP * 4);
    float* es  = (float*)alloc((size_t)n * 4);
    float* ed  = (float*)alloc((size_t)n * 4);
    float* hl  = (float*)alloc((size_t)n * 4);
    int*   deg = (int*)alloc((size_t)n * 4);
    (void)ws_size; (void)n_in; (void)out_size;

    int agg_blocks = (n + 3) / 4;
    int ntiles = (n + 15) / 16;
    int gemm_blocks = (ntiles + 3) / 4;

    hipMemsetAsync(deg, 0, (size_t)n * 4, stream);
    fill_part_kernel<<<8 * 512, 256, 0, stream>>>(ei, deg, col, E, 512);

    // layer 0 (K=128)
    gemm_mfma_kernel<128><<<gemm_blocks, 256, 0, stream>>>(x0, W0, as0, ad0, h, es, ed, n);
    aggregate64_kernel<false><<<agg_blocks, 256, 0, stream>>>(h, es, ed, deg, col, b0,
                                                              xb, n, 1, nullptr, nullptr);
    // layer 1 (K=64)
    gemm_mfma_kernel<64><<<gemm_blocks, 256, 0, stream>>>(xb, W1, as1, ad1, h, es, ed, n);
    aggregate64_kernel<false><<<agg_blocks, 256, 0, stream>>>(h, es, ed, deg, col, b1,
                                                              xb, n, 1, nullptr, nullptr);
    // layer 2 (K=64)
    gemm_mfma_kernel<64><<<gemm_blocks, 256, 0, stream>>>(xb, W2, as2, ad2, h, es, ed, n);
    // layer-2 aggregate fused with Wl projection -> hl
    aggregate64_kernel<true><<<agg_blocks, 256, 0, stream>>>(h, es, ed, deg, col, b2,
                                                             nullptr, n, 1, Wl, hl);
    // final layer aggregation (OUT=1)
    aggregate1_kernel<<<agg_blocks, 256, 0, stream>>>(hl, asl, adl, bl, deg, col,
                                                      (float*)d_out, n);
}